// Round 8
// baseline (64.663 us; speedup 1.0000x reference)
//
#include <hip/hip_runtime.h>

// SRNet via MFMA (v_mfma_f32_32x32x16_f16), D = W * X^T, 2 pixel-groups per
// wave interleaved. ALL weights live in LDS fragment-major (ds_read_b128 at
// lane*16+const, conflict-free); no software patch prefetch (x_in is 4MB =
// L2-resident, TLP hides it); ONE set of 4 accumulator tiles reused across
// all layers caps AGPR at 64. Target: VGPR+AGPR <= 256 -> 2 waves/SIMD
// (rounds 6/7 sat at 292-312 total = 1 wave/SIMD, occupancy 10%).

typedef _Float16 f16x8  __attribute__((ext_vector_type(8)));
typedef _Float16 half2v __attribute__((ext_vector_type(2)));
typedef float    f32x16 __attribute__((ext_vector_type(16)));
typedef unsigned int u32;
typedef u32 u32x4 __attribute__((ext_vector_type(4)));

union FragU { f16x8 v; u32 w[4]; };

__device__ __forceinline__ u32 pkrne(float a, float b) {
    half2v h; h.x = (_Float16)a; h.y = (_Float16)b;
    return __builtin_bit_cast(u32, h);
}
__device__ __forceinline__ u32 pkrtz(float a, float b) {
    return __builtin_bit_cast(u32, __builtin_amdgcn_cvt_pkrtz(a, b));
}
__device__ __forceinline__ u32 pk_relu(u32 a) {
    half2v z = {};
    half2v r = __builtin_elementwise_max(__builtin_bit_cast(half2v, a), z);
    return __builtin_bit_cast(u32, r);
}

__device__ __forceinline__ f32x16 mfma16(const FragU& a, const FragU& b, f32x16 c) {
    return __builtin_amdgcn_mfma_f32_32x32x16_f16(a.v, b.v, c, 0, 0, 0);
}

__device__ __forceinline__ void pl32(u32& x, u32& y) {
    auto r = __builtin_amdgcn_permlane32_swap((int)x, (int)y, false, false);
    x = (u32)r[0]; y = (u32)r[1];
}

__device__ __forceinline__ void calc_coords(int g, int m, int& b, int& hp, int& wp) {
    unsigned P = (unsigned)(g * 32 + m);
    unsigned bb = P / 64516u;            // 254*254
    unsigned rem = P - bb * 64516u;
    unsigned h = rem / 254u;
    b = (int)bb; hp = (int)h; wp = (int)(rem - h * 254u);
}

// coords -> patch loads + output offset (no prefetch variant).
__device__ __forceinline__ void prep_group(const float* __restrict__ x_in,
                                           int g, int m, int lo,
                                           float p[9], u32& ooff) {
    constexpr int OW = 1016;
    int b, hp, wp;
    calc_coords(g, m, b, hp, wp);
    const float* base = x_in + ((size_t)b << 16) + hp * 256 + wp;
#pragma unroll
    for (int i = 0; i < 3; ++i)
#pragma unroll
        for (int j = 0; j < 3; ++j)
            p[i * 3 + j] = base[i * 256 + j];
    ooff = (u32)b * (OW * OW) + (u32)(4 * hp + lo) * OW + 4 * wp;
}

// Init all 4 accumulators (2 tiles x 2 groups) with bias (f32 LDS broadcast).
__device__ __forceinline__ void init_bias(f32x16& a0, f32x16& a1,
                                          f32x16& b0, f32x16& b1v,
                                          const float* __restrict__ bb, int lo) {
#pragma unroll
    for (int mt = 0; mt < 2; ++mt) {
#pragma unroll
        for (int q = 0; q < 4; ++q) {
            const float4 t = *(const float4*)(bb + 32 * mt + 8 * q + 4 * lo);
            f32x16& A = mt ? a1 : a0;
            f32x16& B = mt ? b1v : b0;
            A[4 * q + 0] = t.x; A[4 * q + 1] = t.y;
            A[4 * q + 2] = t.z; A[4 * q + 3] = t.w;
            B[4 * q + 0] = t.x; B[4 * q + 1] = t.y;
            B[4 * q + 2] = t.z; B[4 * q + 3] = t.w;
        }
    }
}

// acc(2 tiles, D-layout, bias pre-added) -> relu -> f16 -> permlane -> B frags
__device__ __forceinline__ void epilogue(const f32x16& A0, const f32x16& A1,
                                         FragU (&B)[4]) {
    u32 ww[2][4][2];
#pragma unroll
    for (int mt = 0; mt < 2; ++mt) {
        const f32x16& A = mt ? A1 : A0;
#pragma unroll
        for (int q = 0; q < 4; ++q) {
            ww[mt][q][0] = pk_relu(pkrtz(A[4 * q + 0], A[4 * q + 1]));
            ww[mt][q][1] = pk_relu(pkrtz(A[4 * q + 2], A[4 * q + 3]));
        }
    }
#pragma unroll
    for (int ks = 0; ks < 4; ++ks) {
#pragma unroll
        for (int p = 0; p < 2; ++p) {
            u32 a = ww[ks >> 1][2 * (ks & 1) + 0][p];
            u32 b = ww[ks >> 1][2 * (ks & 1) + 1][p];
            pl32(a, b);
            B[ks].w[p]     = a;
            B[ks].w[p + 2] = b;
        }
    }
}

__device__ __forceinline__ void pack_B1(const float p[9], int lo, FragU& B1) {
    if (lo == 0) {
        B1.w[0] = pkrtz(p[0], p[1]);
        B1.w[1] = pkrtz(p[2], p[3]);
        B1.w[2] = pkrtz(p[4], p[5]);
        B1.w[3] = pkrtz(p[6], p[7]);
    } else {
        B1.w[0] = pkrtz(p[8], 0.0f);
        B1.w[1] = 0; B1.w[2] = 0; B1.w[3] = 0;
    }
}

__device__ __forceinline__ FragU lds_frag(const u32x4* __restrict__ wlds,
                                          int slot, int lane) {
    u32x4 v = wlds[slot * 64 + lane];
    FragU f;
    f.w[0] = v.x; f.w[1] = v.y; f.w[2] = v.z; f.w[3] = v.w;
    return f;
}

__global__ __launch_bounds__(256, 1) void srnet_mfma(
    const float* __restrict__ x_in,
    const float* __restrict__ sampler_w,
    const float* __restrict__ w1, const float* __restrict__ b1,
    const float* __restrict__ w2, const float* __restrict__ b2,
    const float* __restrict__ w3, const float* __restrict__ b3,
    const float* __restrict__ w4, const float* __restrict__ b4,
    const float* __restrict__ w5, const float* __restrict__ b5,
    const float* __restrict__ w6, const float* __restrict__ b6,
    float* __restrict__ out)
{
    constexpr int NPAIR = 16129;     // (16*254*254/32) / 2
    constexpr int OW    = 1016;

    const int lane = threadIdx.x & 63;
    const int m    = lane & 31;
    const int lo   = lane >> 5;

    // ---- LDS: weight frag slots [38][64] of 16B + f32 biases ----
    // slot 0..1  : w1eff (mt=0,1)
    // slot 2..33 : hidden L*8 + (mt*4+ks)
    // slot 34..37: w6 (ks=0..3)
    __shared__ u32x4 wlds[38 * 64];
    __shared__ __align__(16) float bias_f32[336];

    const float* wptr[4] = { w2, w3, w4, w5 };
    for (int e = threadIdx.x; e < 2048; e += 256) {
        const int L  = e >> 9;
        const int f  = (e >> 6) & 7;
        const int l  = e & 63;
        const int mt = f >> 2, ks = f & 3;
        const float* src = wptr[L] + (32 * mt + (l & 31)) * 64 + 16 * ks + 8 * (l >> 5);
        const float4 f0 = *(const float4*)(src);
        const float4 f1 = *(const float4*)(src + 4);
        u32x4 v;
        v.x = pkrne(f0.x, f0.y); v.y = pkrne(f0.z, f0.w);
        v.z = pkrne(f1.x, f1.y); v.w = pkrne(f1.z, f1.w);
        wlds[(2 + L * 8 + f) * 64 + l] = v;
    }
    // w6 frags (thread t<64 acts as lane t)
    if (threadIdx.x < 64) {
        const int l = threadIdx.x, lm = l & 31, llo = l >> 5;
        const bool vr = (lm < 16);
        const int r6 = vr ? lm : 0;
#pragma unroll
        for (int ks = 0; ks < 4; ++ks) {
            const float* src = w6 + r6 * 64 + 16 * ks + 8 * llo;
            const float4 f0 = *(const float4*)(src);
            const float4 f1 = *(const float4*)(src + 4);
            u32x4 v;
            v.x = vr ? pkrne(f0.x, f0.y) : 0; v.y = vr ? pkrne(f0.z, f0.w) : 0;
            v.z = vr ? pkrne(f1.x, f1.y) : 0; v.w = vr ? pkrne(f1.z, f1.w) : 0;
            wlds[(34 + ks) * 64 + l] = v;
        }
    }
    // w1eff (softmax folded) by threads 64..127 acting as lanes 0..63
    if (threadIdx.x >= 64 && threadIdx.x < 128) {
        const int l = threadIdx.x - 64, lm = l & 31, llo = l >> 5;
        float ws[4][9];
#pragma unroll
        for (int c = 0; c < 4; ++c) {
            float mx = sampler_w[c * 9];
#pragma unroll
            for (int k = 1; k < 9; ++k) mx = fmaxf(mx, sampler_w[c * 9 + k]);
            float e[9]; float sum = 0.f;
#pragma unroll
            for (int k = 0; k < 9; ++k) { e[k] = __expf(sampler_w[c * 9 + k] - mx); sum += e[k]; }
            float inv = 1.f / sum;
#pragma unroll
            for (int k = 0; k < 9; ++k) ws[c][k] = e[k] * inv;
        }
#pragma unroll
        for (int mt = 0; mt < 2; ++mt) {
            const int row = 32 * mt + lm;
            const float4 wr = *(const float4*)(w1 + row * 4);
            float we[9];
#pragma unroll
            for (int k = 0; k < 9; ++k)
                we[k] = wr.x * ws[0][k] + wr.y * ws[1][k] + wr.z * ws[2][k] + wr.w * ws[3][k];
            u32x4 v;
            if (llo == 0) {
                v.x = pkrne(we[0], we[1]); v.y = pkrne(we[2], we[3]);
                v.z = pkrne(we[4], we[5]); v.w = pkrne(we[6], we[7]);
            } else {
                v.x = pkrne(we[8], 0.f); v.y = 0; v.z = 0; v.w = 0;
            }
            wlds[mt * 64 + l] = v;
        }
    }
    for (int i = threadIdx.x; i < 336; i += 256) {
        float v;
        if      (i < 64)  v = b1[i];
        else if (i < 128) v = b2[i - 64];
        else if (i < 192) v = b3[i - 128];
        else if (i < 256) v = b4[i - 192];
        else if (i < 320) v = b5[i - 256];
        else              v = b6[i - 320];
        bias_f32[i] = v;
    }
    __syncthreads();

    // ---- pair loop: wave owns groups (2*pg, 2*pg+1) ----
    const int wid = (int)((blockIdx.x * blockDim.x + threadIdx.x) >> 6);
    const int nw  = (int)((gridDim.x * blockDim.x) >> 6);

    for (int pg = wid; pg < NPAIR; pg += nw) {
        float pa[9], pb[9];
        u32 oa, ob;
        prep_group(x_in, 2 * pg + 0, m, lo, pa, oa);
        prep_group(x_in, 2 * pg + 1, m, lo, pb, ob);

        FragU B1a, B1b;
        pack_B1(pa, lo, B1a);
        pack_B1(pb, lo, B1b);

        // ONE set of accumulators, reused by every layer (caps AGPR at 64)
        f32x16 c0a, c1a, c0b, c1b;

        // ---- layer 1 (bias C-init; w1 frags from LDS) ----
        init_bias(c0a, c1a, c0b, c1b, bias_f32 + 0, lo);
        {
            FragU wA = lds_frag(wlds, 0, lane);
            FragU wB = lds_frag(wlds, 1, lane);
            c0a = mfma16(wA, B1a, c0a);
            c0b = mfma16(wA, B1b, c0b);
            c1a = mfma16(wB, B1a, c1a);
            c1b = mfma16(wB, B1b, c1b);
        }

        FragU Ba[4], Bb[4];
        epilogue(c0a, c1a, Ba);
        epilogue(c0b, c1b, Bb);

        // ---- layers 2..5: weights from LDS (conflict-free b128) ----
#pragma unroll
        for (int L = 0; L < 4; ++L) {
            init_bias(c0a, c1a, c0b, c1b, bias_f32 + 64 * (L + 1), lo);
#pragma unroll
            for (int ks = 0; ks < 4; ++ks) {
                FragU w0 = lds_frag(wlds, 2 + L * 8 + ks,     lane);
                FragU w1l = lds_frag(wlds, 2 + L * 8 + 4 + ks, lane);
                c0a = mfma16(w0,  Ba[ks], c0a);
                c0b = mfma16(w0,  Bb[ks], c0b);
                c1a = mfma16(w1l, Ba[ks], c1a);
                c1b = mfma16(w1l, Bb[ks], c1b);
            }
            epilogue(c0a, c1a, Ba);
            epilogue(c0b, c1b, Bb);
        }

        // ---- layer 6 (reuses c0a/c0b; b6 C-init; rows 16..31 unused) ----
        {
            const float4 t0 = *(const float4*)(bias_f32 + 320 + 4 * lo);
            const float4 t1 = *(const float4*)(bias_f32 + 320 + 8 + 4 * lo);
#pragma unroll
            for (int j = 0; j < 4; ++j) {
                c0a[j]      = ((const float*)&t0)[j];
                c0a[4 + j]  = ((const float*)&t1)[j];
                c0a[8 + j]  = 0.f;
                c0a[12 + j] = 0.f;
            }
            c0b = c0a;
        }
#pragma unroll
        for (int ks = 0; ks < 4; ++ks) {
            FragU w6f = lds_frag(wlds, 34 + ks, lane);
            c0a = mfma16(w6f, Ba[ks], c0a);
            c0b = mfma16(w6f, Bb[ks], c0b);
        }

        // ---- pixel-shuffle stores ----
        {
            float* obase = out + oa;
            *(float4*)(obase)          = make_float4(c0a[0], c0a[1], c0a[2], c0a[3]);
            *(float4*)(obase + 2 * OW) = make_float4(c0a[4], c0a[5], c0a[6], c0a[7]);
            obase = out + ob;
            *(float4*)(obase)          = make_float4(c0b[0], c0b[1], c0b[2], c0b[3]);
            *(float4*)(obase + 2 * OW) = make_float4(c0b[4], c0b[5], c0b[6], c0b[7]);
        }
    }
}

extern "C" void kernel_launch(void* const* d_in, const int* in_sizes, int n_in,
                              void* d_out, int out_size, void* d_ws, size_t ws_size,
                              hipStream_t stream)
{
    const float* x_in      = (const float*)d_in[0];
    const float* sampler_w = (const float*)d_in[1];
    // d_in[2] = sampler_b (reference multiplies it by 0 -> unused)
    const float* w1 = (const float*)d_in[3];
    const float* b1 = (const float*)d_in[4];
    const float* w2 = (const float*)d_in[5];
    const float* b2 = (const float*)d_in[6];
    const float* w3 = (const float*)d_in[7];
    const float* b3 = (const float*)d_in[8];
    const float* w4 = (const float*)d_in[9];
    const float* b4 = (const float*)d_in[10];
    const float* w5 = (const float*)d_in[11];
    const float* b5 = (const float*)d_in[12];
    const float* w6 = (const float*)d_in[13];
    const float* b6 = (const float*)d_in[14];
    float* out = (float*)d_out;

    dim3 grid(512);   // 2 blocks/CU; register budget sized for 2 waves/SIMD
    dim3 block(256);
    hipLaunchKernelGGL(srnet_mfma, grid, block, 0, stream,
                       x_in, sampler_w, w1, b1, w2, b2, w3, b3,
                       w4, b4, w5, b5, w6, b6, out);
}